// Round 1
// baseline (736.326 us; speedup 1.0000x reference)
//
#include <hip/hip_runtime.h>

#define N_NODES 50000
#define E_EDGES 1600000
#define NEG 0.2f
#define ALPHA1_BLOCKS 2048

__device__ __forceinline__ float lrelu(float x){ return x > 0.f ? x : NEG*x; }
__device__ __forceinline__ float bcastlane(float v, int k){
    return __int_as_float(__builtin_amdgcn_readlane(__float_as_int(v), k));
}

// small[] layout (floats): [0..16) unused, [16..32) mean, [32..96) WeAtt1[k*4+h],
// [96..160) WeAtt2, [160..164) aeloop1, [164..168) aeloop2

__global__ void k_prep1(const float* __restrict__ We1, const float* __restrict__ atte1,
                        const float* __restrict__ We2, const float* __restrict__ atte2,
                        float* __restrict__ small){
    int t = threadIdx.x;            // 64 threads: t = k*4+h
    int k = t >> 2, hh = t & 3;
    float w1 = 0.f, w2 = 0.f;
    for (int c = 0; c < 16; ++c){
        w1 = fmaf(We1[k*64 + hh*16 + c], atte1[hh*16 + c], w1);
        w2 = fmaf(We2[k*64 + hh*16 + c], atte2[hh*16 + c], w2);
    }
    small[32 + t] = w1;
    small[96 + t] = w2;
}

__global__ __launch_bounds__(256) void k_hist(const int* __restrict__ dst, int* __restrict__ deg){
    int e = blockIdx.x*256 + threadIdx.x;
    if (e < E_EDGES) atomicAdd(&deg[dst[e]], 1);
}

__global__ __launch_bounds__(1024) void k_scan(const int* __restrict__ deg,
                                               int* __restrict__ base, int* __restrict__ cursor){
    __shared__ int part[1024];
    const int CH = (N_NODES + 1023)/1024;   // 49
    int t = threadIdx.x;
    int lo = t*CH;
    int hi = lo + CH; if (hi > N_NODES) hi = N_NODES;
    int s = 0;
    for (int i = lo; i < hi; ++i) s += deg[i];
    part[t] = s;
    __syncthreads();
    for (int off = 1; off < 1024; off <<= 1){
        int v = (t >= off) ? part[t-off] : 0;
        __syncthreads();
        part[t] += v;
        __syncthreads();
    }
    int ex = (t > 0) ? part[t-1] : 0;
    for (int i = lo; i < hi; ++i){ base[i] = ex; cursor[i] = ex; ex += deg[i]; }
    if (t == 0) base[N_NODES] = part[1023];
}

__global__ __launch_bounds__(256) void k_scatter(const int* __restrict__ src, const int* __restrict__ dst,
                                                 int* __restrict__ cursor, int* __restrict__ csr_src,
                                                 int* __restrict__ pos_arr){
    int e = blockIdx.x*256 + threadIdx.x;
    if (e >= E_EDGES) return;
    int d = dst[e];
    int p = atomicAdd(&cursor[d], 1);
    csr_src[p] = src[e];
    pos_arr[e] = p;
}

// h = in @ W  (N x FIN @ FIN x 64), a_s/a_d per (node, head). One wave per node.
template<int FIN>
__global__ __launch_bounds__(256) void k_node(const float* __restrict__ in, const float* __restrict__ W,
                                              const float* __restrict__ att_s, const float* __restrict__ att_d,
                                              float* __restrict__ h, float* __restrict__ a_s,
                                              float* __restrict__ a_d){
    __shared__ float Wl[FIN*64];
    for (int i = threadIdx.x; i < FIN*64; i += 256) Wl[i] = W[i];
    __syncthreads();
    int lane = threadIdx.x & 63;
    int node = blockIdx.x*4 + (threadIdx.x >> 6);   // N % 4 == 0, always valid
    const float* row = in + (size_t)node*FIN;
    float x0 = row[lane];
    float x1 = 0.f;
    if constexpr (FIN == 128) x1 = row[64 + lane];
    float acc = 0.f;
#pragma unroll
    for (int k = 0; k < 64; ++k)
        acc = fmaf(bcastlane(x0, k), Wl[k*64 + lane], acc);
    if constexpr (FIN == 128){
#pragma unroll
        for (int k = 0; k < 64; ++k)
            acc = fmaf(bcastlane(x1, k), Wl[(64+k)*64 + lane], acc);
    }
    h[(size_t)node*64 + lane] = acc;
    float ps = acc * att_s[lane];
    float pd = acc * att_d[lane];
    ps += __shfl_xor(ps,1); ps += __shfl_xor(ps,2); ps += __shfl_xor(ps,4); ps += __shfl_xor(ps,8);
    pd += __shfl_xor(pd,1); pd += __shfl_xor(pd,2); pd += __shfl_xor(pd,4); pd += __shfl_xor(pd,8);
    if ((lane & 15) == 0){
        a_s[node*4 + (lane>>4)] = ps;
        a_d[node*4 + (lane>>4)] = pd;
    }
}

// Layer-1 edge pass: alpha1 -> alpha_csr[pos], a_e(layer2) -> ae2out, and column-sums of ea.
__global__ __launch_bounds__(256) void k_alpha1(const int* __restrict__ src, const int* __restrict__ dst,
                                                const float* __restrict__ ea, const float* __restrict__ small,
                                                const float* __restrict__ a_s, const float* __restrict__ a_d,
                                                const int* __restrict__ pos_arr, float* __restrict__ alpha_csr,
                                                float* __restrict__ ae2out, float* __restrict__ partials){
    __shared__ float w1[64], w2[64];
    __shared__ float red[64];
    if (threadIdx.x < 64){ w1[threadIdx.x] = small[32+threadIdx.x]; w2[threadIdx.x] = small[96+threadIdx.x]; }
    __syncthreads();
    float cs[16];
#pragma unroll
    for (int k = 0; k < 16; ++k) cs[k] = 0.f;
    int stride = gridDim.x*blockDim.x;
    for (int e = blockIdx.x*blockDim.x + threadIdx.x; e < E_EDGES; e += stride){
        const float4* eap = (const float4*)(ea + (size_t)e*16);
        float ae1[4] = {0,0,0,0}, ae2[4] = {0,0,0,0};
#pragma unroll
        for (int q = 0; q < 4; ++q){
            float4 v4 = eap[q];
            float vv[4] = {v4.x, v4.y, v4.z, v4.w};
#pragma unroll
            for (int r = 0; r < 4; ++r){
                int k = q*4 + r;
                float xv = vv[r];
                cs[k] += xv;
#pragma unroll
                for (int hh = 0; hh < 4; ++hh){
                    ae1[hh] = fmaf(xv, w1[k*4+hh], ae1[hh]);
                    ae2[hh] = fmaf(xv, w2[k*4+hh], ae2[hh]);
                }
            }
        }
        int s = src[e], d = dst[e], p = pos_arr[e];
        const float4 as4 = *(const float4*)(a_s + (size_t)s*4);
        const float4 ad4 = *(const float4*)(a_d + (size_t)d*4);
        float4 o, e2;
        o.x = lrelu(as4.x + ad4.x + ae1[0]);
        o.y = lrelu(as4.y + ad4.y + ae1[1]);
        o.z = lrelu(as4.z + ad4.z + ae1[2]);
        o.w = lrelu(as4.w + ad4.w + ae1[3]);
        e2.x = ae2[0]; e2.y = ae2[1]; e2.z = ae2[2]; e2.w = ae2[3];
        *(float4*)(alpha_csr + (size_t)p*4) = o;
        *(float4*)(ae2out   + (size_t)e*4) = e2;
    }
    // block-reduce column sums -> partials[block][16]
#pragma unroll
    for (int k = 0; k < 16; ++k){
        float v = cs[k];
        v += __shfl_xor(v,1); v += __shfl_xor(v,2); v += __shfl_xor(v,4);
        v += __shfl_xor(v,8); v += __shfl_xor(v,16); v += __shfl_xor(v,32);
        if ((threadIdx.x & 63) == 0) red[k*4 + (threadIdx.x>>6)] = v;
    }
    __syncthreads();
    if (threadIdx.x < 16){
        float v = red[threadIdx.x*4] + red[threadIdx.x*4+1] + red[threadIdx.x*4+2] + red[threadIdx.x*4+3];
        partials[blockIdx.x*16 + threadIdx.x] = v;
    }
}

__global__ __launch_bounds__(256) void k_prep2(float* __restrict__ small, const float* __restrict__ partials){
    __shared__ float sm[256];
    __shared__ float mean_s[16];
    int t = threadIdx.x;
    float v = 0.f;
    for (int r = (t>>4); r < ALPHA1_BLOCKS; r += 16) v += partials[r*16 + (t&15)];
    sm[t] = v;
    __syncthreads();
    if (t < 16){
        float s = 0.f;
#pragma unroll
        for (int i = 0; i < 16; ++i) s += sm[t + 16*i];
        float m = s * (1.0f/(float)E_EDGES);
        mean_s[t] = m; small[16+t] = m;
    }
    __syncthreads();
    if (t < 4){
        float a1 = 0.f, a2 = 0.f;
#pragma unroll
        for (int k = 0; k < 16; ++k){
            a1 = fmaf(mean_s[k], small[32 + k*4 + t], a1);
            a2 = fmaf(mean_s[k], small[96 + k*4 + t], a2);
        }
        small[160+t] = a1; small[164+t] = a2;
    }
}

__global__ __launch_bounds__(256) void k_alpha2(const int* __restrict__ src, const int* __restrict__ dst,
                                                const float* __restrict__ ae2,
                                                const float* __restrict__ a_s, const float* __restrict__ a_d,
                                                const int* __restrict__ pos_arr, float* __restrict__ alpha_csr){
    int e = blockIdx.x*256 + threadIdx.x;
    if (e >= E_EDGES) return;
    int s = src[e], d = dst[e], p = pos_arr[e];
    const float4 ae  = *(const float4*)(ae2 + (size_t)e*4);
    const float4 as4 = *(const float4*)(a_s + (size_t)s*4);
    const float4 ad4 = *(const float4*)(a_d + (size_t)d*4);
    float4 o;
    o.x = lrelu(as4.x + ad4.x + ae.x);
    o.y = lrelu(as4.y + ad4.y + ae.y);
    o.z = lrelu(as4.z + ad4.z + ae.z);
    o.w = lrelu(as4.w + ad4.w + ae.w);
    *(float4*)(alpha_csr + (size_t)p*4) = o;
}

// One wave per node, lane = head*16+chan. Online softmax, no atomics.
__global__ __launch_bounds__(256) void k_agg(const float* __restrict__ alpha_csr, const int* __restrict__ csr_src,
                                             const int* __restrict__ base, const float* __restrict__ h,
                                             const float* __restrict__ a_s, const float* __restrict__ a_d,
                                             const float* __restrict__ aeloop, const float* __restrict__ bias,
                                             float* __restrict__ out){
    int lane = threadIdx.x & 63;
    int n = blockIdx.x*4 + (threadIdx.x >> 6);
    int hh = lane >> 4;
    float aL = a_s[n*4+hh] + a_d[n*4+hh] + aeloop[hh];
    aL = lrelu(aL);
    float m = aL, s = 1.f;
    float acc = h[(size_t)n*64 + lane];          // self-loop message, weight exp(aL-m)=1
    int b0 = base[n], b1 = base[n+1];
    float a_c = 0.f; int si_c = 0;
    if (b0 < b1){ a_c = alpha_csr[(size_t)b0*4 + hh]; si_c = csr_src[b0]; }
    for (int p = b0; p < b1; ++p){
        float hv = h[(size_t)si_c*64 + lane];    // issue gather early
        float a_n = 0.f; int si_n = 0;
        if (p+1 < b1){ a_n = alpha_csr[(size_t)(p+1)*4 + hh]; si_n = csr_src[p+1]; }
        float mn  = fmaxf(m, a_c);
        float scl = __expf(m - mn);
        float pe  = __expf(a_c - mn);
        s   = fmaf(s, scl, pe);
        acc = fmaf(acc, scl, pe*hv);
        m = mn;
        a_c = a_n; si_c = si_n;
    }
    float val = acc / (s + 1e-16f) + bias[lane];
    out[(size_t)n*64 + lane] = fmaxf(val, 0.f);
}

__global__ __launch_bounds__(256) void k_head(const float* __restrict__ h2,
                                              const float* __restrict__ lw1, const float* __restrict__ lb1,
                                              const float* __restrict__ lw2, const float* __restrict__ lb2,
                                              float* __restrict__ out){
    int n = blockIdx.x*256 + threadIdx.x;
    if (n >= N_NODES) return;
    float y16[16];
#pragma unroll
    for (int j = 0; j < 16; ++j) y16[j] = lb1[j];
    const float4* hp = (const float4*)(h2 + (size_t)n*64);
#pragma unroll
    for (int k4 = 0; k4 < 16; ++k4){
        float4 hv = hp[k4];
        float hvv[4] = {hv.x, hv.y, hv.z, hv.w};
#pragma unroll
        for (int r = 0; r < 4; ++r){
            float x = hvv[r];
            int k = k4*4 + r;
#pragma unroll
            for (int j = 0; j < 16; ++j) y16[j] = fmaf(x, lw1[k*16+j], y16[j]);
        }
    }
    float y[40];
#pragma unroll
    for (int o = 0; o < 40; ++o) y[o] = lb2[o];
#pragma unroll
    for (int j = 0; j < 16; ++j){
        float x = y16[j];
#pragma unroll
        for (int o = 0; o < 40; ++o) y[o] = fmaf(x, lw2[j*40+o], y[o]);
    }
    float mx = y[0];
#pragma unroll
    for (int o = 1; o < 40; ++o) mx = fmaxf(mx, y[o]);
    float sum = 0.f;
#pragma unroll
    for (int o = 0; o < 40; ++o) sum += __expf(y[o] - mx);
    float ls = __logf(sum) + mx;
    float* op = out + (size_t)n*40;
#pragma unroll
    for (int o = 0; o < 40; ++o) op[o] = y[o] - ls;
}

extern "C" void kernel_launch(void* const* d_in, const int* in_sizes, int n_in,
                              void* d_out, int out_size, void* d_ws, size_t ws_size,
                              hipStream_t stream){
    const float* x     = (const float*)d_in[0];
    const int*   ei    = (const int*)  d_in[1];
    const float* ea    = (const float*)d_in[2];
    const float* W1    = (const float*)d_in[3];
    const float* atts1 = (const float*)d_in[4];
    const float* attd1 = (const float*)d_in[5];
    const float* We1   = (const float*)d_in[6];
    const float* atte1 = (const float*)d_in[7];
    const float* b1    = (const float*)d_in[8];
    const float* W2    = (const float*)d_in[9];
    const float* atts2 = (const float*)d_in[10];
    const float* attd2 = (const float*)d_in[11];
    const float* We2   = (const float*)d_in[12];
    const float* atte2 = (const float*)d_in[13];
    const float* b2    = (const float*)d_in[14];
    const float* lw1   = (const float*)d_in[15];
    const float* lb1   = (const float*)d_in[16];
    const float* lw2   = (const float*)d_in[17];
    const float* lb2   = (const float*)d_in[18];
    float* outp = (float*)d_out;

    const int* srcp = ei;
    const int* dstp = ei + E_EDGES;

    char* ws = (char*)d_ws;
    size_t off = 0;
    auto alloc = [&](size_t bytes) -> void* {
        void* p = ws + off;
        off = (off + bytes + 255) & ~(size_t)255;
        return p;
    };
    float* smallf    = (float*)alloc(256*sizeof(float));
    float* partials  = (float*)alloc((size_t)ALPHA1_BLOCKS*16*sizeof(float));
    int*   deg       = (int*)  alloc((size_t)N_NODES*sizeof(int));
    int*   base      = (int*)  alloc((size_t)(N_NODES+1)*sizeof(int));
    int*   cursor    = (int*)  alloc((size_t)N_NODES*sizeof(int));
    int*   pos_arr   = (int*)  alloc((size_t)E_EDGES*sizeof(int));
    int*   csr_src   = (int*)  alloc((size_t)E_EDGES*sizeof(int));
    float* ae2       = (float*)alloc((size_t)E_EDGES*4*sizeof(float));
    float* alpha_csr = (float*)alloc((size_t)E_EDGES*4*sizeof(float));
    float* hbuf      = (float*)alloc((size_t)N_NODES*64*sizeof(float));
    float* obuf      = (float*)alloc((size_t)N_NODES*64*sizeof(float));
    float* asb       = (float*)alloc((size_t)N_NODES*4*sizeof(float));
    float* adb       = (float*)alloc((size_t)N_NODES*4*sizeof(float));

    const int EB = (E_EDGES + 255)/256;   // 6250
    const int NB = N_NODES/4;             // 12500
    const int HB = (N_NODES + 255)/256;   // 196

    hipMemsetAsync(deg, 0, (size_t)N_NODES*sizeof(int), stream);
    k_prep1<<<1, 64, 0, stream>>>(We1, atte1, We2, atte2, smallf);
    k_hist<<<EB, 256, 0, stream>>>(dstp, deg);
    k_scan<<<1, 1024, 0, stream>>>(deg, base, cursor);
    k_scatter<<<EB, 256, 0, stream>>>(srcp, dstp, cursor, csr_src, pos_arr);

    // ---- layer 1 ----
    k_node<128><<<NB, 256, 0, stream>>>(x, W1, atts1, attd1, hbuf, asb, adb);
    k_alpha1<<<ALPHA1_BLOCKS, 256, 0, stream>>>(srcp, dstp, ea, smallf, asb, adb,
                                                pos_arr, alpha_csr, ae2, partials);
    k_prep2<<<1, 256, 0, stream>>>(smallf, partials);
    k_agg<<<NB, 256, 0, stream>>>(alpha_csr, csr_src, base, hbuf, asb, adb,
                                  smallf + 160, b1, obuf);

    // ---- layer 2 ----
    k_node<64><<<NB, 256, 0, stream>>>(obuf, W2, atts2, attd2, hbuf, asb, adb);
    k_alpha2<<<EB, 256, 0, stream>>>(srcp, dstp, ae2, asb, adb, pos_arr, alpha_csr);
    k_agg<<<NB, 256, 0, stream>>>(alpha_csr, csr_src, base, hbuf, asb, adb,
                                  smallf + 164, b2, obuf);

    // ---- head ----
    k_head<<<HB, 256, 0, stream>>>(obuf, lw1, lb1, lw2, lb2, outp);
}

// Round 2
// 628.838 us; speedup vs baseline: 1.1709x; 1.1709x over previous
//
#include <hip/hip_runtime.h>

#define N_NODES 50000
#define E_EDGES 1600000
#define NEG 0.2f
#define EDGE_BLOCKS 2048

__device__ __forceinline__ float lrelu(float x){ return x > 0.f ? x : NEG*x; }
__device__ __forceinline__ float bcastlane(float v, int k){
    return __int_as_float(__builtin_amdgcn_readlane(__float_as_int(v), k));
}
__device__ __forceinline__ unsigned bf16rn(float x){
    unsigned u = __float_as_uint(x);
    return (u + 0x7FFFu + ((u >> 16) & 1u)) >> 16;
}

// small[] layout (floats): [16..32) mean, [32..96) WeAtt1[k*4+h], [96..160) WeAtt2,
// [160..164) aeloop1, [164..168) aeloop2

__global__ void k_prep1(const float* __restrict__ We1, const float* __restrict__ atte1,
                        const float* __restrict__ We2, const float* __restrict__ atte2,
                        float* __restrict__ small){
    int t = threadIdx.x;            // 64 threads: t = k*4+h
    int k = t >> 2, hh = t & 3;
    float w1 = 0.f, w2 = 0.f;
    for (int c = 0; c < 16; ++c){
        w1 = fmaf(We1[k*64 + hh*16 + c], atte1[hh*16 + c], w1);
        w2 = fmaf(We2[k*64 + hh*16 + c], atte2[hh*16 + c], w2);
    }
    small[32 + t] = w1;
    small[96 + t] = w2;
}

__global__ __launch_bounds__(256) void k_hist(const int4* __restrict__ dst4, int* __restrict__ deg){
    int i = blockIdx.x*256 + threadIdx.x;
    if (i < E_EDGES/4){
        int4 v = dst4[i];
        atomicAdd(&deg[v.x], 1);
        atomicAdd(&deg[v.y], 1);
        atomicAdd(&deg[v.z], 1);
        atomicAdd(&deg[v.w], 1);
    }
}

__global__ __launch_bounds__(1024) void k_scan(const int* __restrict__ deg,
                                               int* __restrict__ base, int* __restrict__ cursor){
    __shared__ int part[1024];
    const int CH = (N_NODES + 1023)/1024;   // 49
    int t = threadIdx.x;
    int lo = t*CH;
    int hi = lo + CH; if (hi > N_NODES) hi = N_NODES;
    int s = 0;
    for (int i = lo; i < hi; ++i) s += deg[i];
    part[t] = s;
    __syncthreads();
    for (int off = 1; off < 1024; off <<= 1){
        int v = (t >= off) ? part[t-off] : 0;
        __syncthreads();
        part[t] += v;
        __syncthreads();
    }
    int ex = (t > 0) ? part[t-1] : 0;
    for (int i = lo; i < hi; ++i){ base[i] = ex; cursor[i] = ex; ex += deg[i]; }
    if (t == 0) base[N_NODES] = part[1023];
}

// Fused edge pass: ae1 (fp32) + ae2 (bf16) -> one scattered 32B record at CSR pos.
// Also reduces column sums of ea for the mean self-loop attr.
__global__ __launch_bounds__(256) void k_edges(const int* __restrict__ src, const int* __restrict__ dst,
                                               const float* __restrict__ ea, const float* __restrict__ small,
                                               int* __restrict__ cursor, float4* __restrict__ rec,
                                               float* __restrict__ partials){
    __shared__ float w1[64], w2[64];
    __shared__ float red[64];
    if (threadIdx.x < 64){ w1[threadIdx.x] = small[32+threadIdx.x]; w2[threadIdx.x] = small[96+threadIdx.x]; }
    __syncthreads();
    float cs[16];
#pragma unroll
    for (int k = 0; k < 16; ++k) cs[k] = 0.f;
    int stride = gridDim.x*blockDim.x;
    for (int e = blockIdx.x*blockDim.x + threadIdx.x; e < E_EDGES; e += stride){
        const float4* eap = (const float4*)(ea + (size_t)e*16);
        float ae1[4] = {0,0,0,0}, ae2[4] = {0,0,0,0};
#pragma unroll
        for (int q = 0; q < 4; ++q){
            float4 v4 = eap[q];
            float vv[4] = {v4.x, v4.y, v4.z, v4.w};
#pragma unroll
            for (int r = 0; r < 4; ++r){
                int k = q*4 + r;
                float xv = vv[r];
                cs[k] += xv;
#pragma unroll
                for (int hh = 0; hh < 4; ++hh){
                    ae1[hh] = fmaf(xv, w1[k*4+hh], ae1[hh]);
                    ae2[hh] = fmaf(xv, w2[k*4+hh], ae2[hh]);
                }
            }
        }
        int s = src[e], d = dst[e];
        int p = atomicAdd(&cursor[d], 1);
        unsigned pk01 = bf16rn(ae2[0]) | (bf16rn(ae2[1]) << 16);
        unsigned pk23 = bf16rn(ae2[2]) | (bf16rn(ae2[3]) << 16);
        float4 r0, r1;
        r0.x = __int_as_float(s); r0.y = ae1[0]; r0.z = ae1[1]; r0.w = ae1[2];
        r1.x = ae1[3]; r1.y = __uint_as_float(pk01); r1.z = __uint_as_float(pk23); r1.w = 0.f;
        rec[(size_t)p*2]     = r0;
        rec[(size_t)p*2 + 1] = r1;
    }
#pragma unroll
    for (int k = 0; k < 16; ++k){
        float v = cs[k];
        v += __shfl_xor(v,1); v += __shfl_xor(v,2); v += __shfl_xor(v,4);
        v += __shfl_xor(v,8); v += __shfl_xor(v,16); v += __shfl_xor(v,32);
        if ((threadIdx.x & 63) == 0) red[k*4 + (threadIdx.x>>6)] = v;
    }
    __syncthreads();
    if (threadIdx.x < 16){
        float v = red[threadIdx.x*4] + red[threadIdx.x*4+1] + red[threadIdx.x*4+2] + red[threadIdx.x*4+3];
        partials[blockIdx.x*16 + threadIdx.x] = v;
    }
}

__global__ __launch_bounds__(256) void k_prep2(float* __restrict__ small, const float* __restrict__ partials){
    __shared__ float sm[256];
    __shared__ float mean_s[16];
    int t = threadIdx.x;
    float v = 0.f;
    for (int r = (t>>4); r < EDGE_BLOCKS; r += 16) v += partials[r*16 + (t&15)];
    sm[t] = v;
    __syncthreads();
    if (t < 16){
        float s = 0.f;
#pragma unroll
        for (int i = 0; i < 16; ++i) s += sm[t + 16*i];
        float m = s * (1.0f/(float)E_EDGES);
        mean_s[t] = m; small[16+t] = m;
    }
    __syncthreads();
    if (t < 4){
        float a1 = 0.f, a2 = 0.f;
#pragma unroll
        for (int k = 0; k < 16; ++k){
            a1 = fmaf(mean_s[k], small[32 + k*4 + t], a1);
            a2 = fmaf(mean_s[k], small[96 + k*4 + t], a2);
        }
        small[160+t] = a1; small[164+t] = a2;
    }
}

// h = in @ W  (N x FIN @ FIN x 64), a_s/a_d per (node, head). One wave per node.
template<int FIN>
__global__ __launch_bounds__(256) void k_node(const float* __restrict__ in, const float* __restrict__ W,
                                              const float* __restrict__ att_s, const float* __restrict__ att_d,
                                              float* __restrict__ h, float* __restrict__ a_s,
                                              float* __restrict__ a_d){
    __shared__ float Wl[FIN*64];
    for (int i = threadIdx.x; i < FIN*64; i += 256) Wl[i] = W[i];
    __syncthreads();
    int lane = threadIdx.x & 63;
    int node = blockIdx.x*4 + (threadIdx.x >> 6);   // N % 4 == 0, always valid
    const float* row = in + (size_t)node*FIN;
    float x0 = row[lane];
    float x1 = 0.f;
    if constexpr (FIN == 128) x1 = row[64 + lane];
    float acc = 0.f;
#pragma unroll
    for (int k = 0; k < 64; ++k)
        acc = fmaf(bcastlane(x0, k), Wl[k*64 + lane], acc);
    if constexpr (FIN == 128){
#pragma unroll
        for (int k = 0; k < 64; ++k)
            acc = fmaf(bcastlane(x1, k), Wl[(64+k)*64 + lane], acc);
    }
    h[(size_t)node*64 + lane] = acc;
    float ps = acc * att_s[lane];
    float pd = acc * att_d[lane];
    ps += __shfl_xor(ps,1); ps += __shfl_xor(ps,2); ps += __shfl_xor(ps,4); ps += __shfl_xor(ps,8);
    pd += __shfl_xor(pd,1); pd += __shfl_xor(pd,2); pd += __shfl_xor(pd,4); pd += __shfl_xor(pd,8);
    if ((lane & 15) == 0){
        a_s[node*4 + (lane>>4)] = ps;
        a_d[node*4 + (lane>>4)] = pd;
    }
}

// One wave per node, lane = head*16+chan. Online softmax, alpha computed on the fly.
// L==1: ae fp32 from r0.yzw/r1.x ; L==2: ae bf16-packed in r1.y/r1.z.
template<int L>
__global__ __launch_bounds__(256) void k_agg(const float4* __restrict__ rec, const int* __restrict__ base,
                                             const float* __restrict__ h,
                                             const float* __restrict__ a_s, const float* __restrict__ a_d,
                                             const float* __restrict__ aeloop, const float* __restrict__ bias,
                                             float* __restrict__ out){
    int lane = threadIdx.x & 63;
    int n = blockIdx.x*4 + (threadIdx.x >> 6);
    int hh = lane >> 4;
    float ad_v = a_d[n*4+hh];
    float aL = lrelu(a_s[n*4+hh] + ad_v + aeloop[hh]);
    float m = aL, s = 1.f;
    float acc = h[(size_t)n*64 + lane];          // self-loop message, weight exp(aL-m)=1
    int b0 = base[n], b1 = base[n+1];
    float4 r0c, r1c;
    if (b0 < b1){ r0c = rec[(size_t)b0*2]; r1c = rec[(size_t)b0*2+1]; }
    for (int p = b0; p < b1; ++p){
        int si = __float_as_int(r0c.x);
        float aev;
        if constexpr (L == 1){
            aev = (hh == 0) ? r0c.y : (hh == 1) ? r0c.z : (hh == 2) ? r0c.w : r1c.x;
        } else {
            unsigned pk = __float_as_uint((hh < 2) ? r1c.y : r1c.z);
            aev = __uint_as_float((hh & 1) ? (pk & 0xFFFF0000u) : (pk << 16));
        }
        float hv   = h[(size_t)si*64 + lane];    // gather, LLC-resident
        float as_v = a_s[si*4 + hh];             // gather, L2-resident
        if (p+1 < b1){ r0c = rec[(size_t)(p+1)*2]; r1c = rec[(size_t)(p+1)*2+1]; }
        float al  = lrelu(as_v + ad_v + aev);
        float mn  = fmaxf(m, al);
        float scl = __expf(m - mn);
        float pe  = __expf(al - mn);
        s   = fmaf(s, scl, pe);
        acc = fmaf(acc, scl, pe*hv);
        m = mn;
    }
    float val = acc / (s + 1e-16f) + bias[lane];
    out[(size_t)n*64 + lane] = fmaxf(val, 0.f);
}

__global__ __launch_bounds__(256) void k_head(const float* __restrict__ h2,
                                              const float* __restrict__ lw1, const float* __restrict__ lb1,
                                              const float* __restrict__ lw2, const float* __restrict__ lb2,
                                              float* __restrict__ out){
    int n = blockIdx.x*256 + threadIdx.x;
    if (n >= N_NODES) return;
    float y16[16];
#pragma unroll
    for (int j = 0; j < 16; ++j) y16[j] = lb1[j];
    const float4* hp = (const float4*)(h2 + (size_t)n*64);
#pragma unroll
    for (int k4 = 0; k4 < 16; ++k4){
        float4 hv = hp[k4];
        float hvv[4] = {hv.x, hv.y, hv.z, hv.w};
#pragma unroll
        for (int r = 0; r < 4; ++r){
            float x = hvv[r];
            int k = k4*4 + r;
#pragma unroll
            for (int j = 0; j < 16; ++j) y16[j] = fmaf(x, lw1[k*16+j], y16[j]);
        }
    }
    float y[40];
#pragma unroll
    for (int o = 0; o < 40; ++o) y[o] = lb2[o];
#pragma unroll
    for (int j = 0; j < 16; ++j){
        float x = y16[j];
#pragma unroll
        for (int o = 0; o < 40; ++o) y[o] = fmaf(x, lw2[j*40+o], y[o]);
    }
    float mx = y[0];
#pragma unroll
    for (int o = 1; o < 40; ++o) mx = fmaxf(mx, y[o]);
    float sum = 0.f;
#pragma unroll
    for (int o = 0; o < 40; ++o) sum += __expf(y[o] - mx);
    float ls = __logf(sum) + mx;
    float* op = out + (size_t)n*40;
#pragma unroll
    for (int o = 0; o < 40; ++o) op[o] = y[o] - ls;
}

extern "C" void kernel_launch(void* const* d_in, const int* in_sizes, int n_in,
                              void* d_out, int out_size, void* d_ws, size_t ws_size,
                              hipStream_t stream){
    const float* x     = (const float*)d_in[0];
    const int*   ei    = (const int*)  d_in[1];
    const float* ea    = (const float*)d_in[2];
    const float* W1    = (const float*)d_in[3];
    const float* atts1 = (const float*)d_in[4];
    const float* attd1 = (const float*)d_in[5];
    const float* We1   = (const float*)d_in[6];
    const float* atte1 = (const float*)d_in[7];
    const float* b1    = (const float*)d_in[8];
    const float* W2    = (const float*)d_in[9];
    const float* atts2 = (const float*)d_in[10];
    const float* attd2 = (const float*)d_in[11];
    const float* We2   = (const float*)d_in[12];
    const float* atte2 = (const float*)d_in[13];
    const float* b2    = (const float*)d_in[14];
    const float* lw1   = (const float*)d_in[15];
    const float* lb1   = (const float*)d_in[16];
    const float* lw2   = (const float*)d_in[17];
    const float* lb2   = (const float*)d_in[18];
    float* outp = (float*)d_out;

    const int* srcp = ei;
    const int* dstp = ei + E_EDGES;

    char* ws = (char*)d_ws;
    size_t off = 0;
    auto alloc = [&](size_t bytes) -> void* {
        void* p = ws + off;
        off = (off + bytes + 255) & ~(size_t)255;
        return p;
    };
    float*  smallf   = (float*) alloc(256*sizeof(float));
    float*  partials = (float*) alloc((size_t)EDGE_BLOCKS*16*sizeof(float));
    int*    deg      = (int*)   alloc((size_t)N_NODES*sizeof(int));
    int*    base     = (int*)   alloc((size_t)(N_NODES+1)*sizeof(int));
    int*    cursor   = (int*)   alloc((size_t)N_NODES*sizeof(int));
    float4* rec      = (float4*)alloc((size_t)E_EDGES*32);
    float*  hbuf     = (float*) alloc((size_t)N_NODES*64*sizeof(float));
    float*  obuf     = (float*) alloc((size_t)N_NODES*64*sizeof(float));
    float*  asb      = (float*) alloc((size_t)N_NODES*4*sizeof(float));
    float*  adb      = (float*) alloc((size_t)N_NODES*4*sizeof(float));

    const int NB = N_NODES/4;             // 12500
    const int HB = (N_NODES + 255)/256;   // 196

    hipMemsetAsync(deg, 0, (size_t)N_NODES*sizeof(int), stream);
    k_prep1<<<1, 64, 0, stream>>>(We1, atte1, We2, atte2, smallf);
    k_hist<<<(E_EDGES/4 + 255)/256, 256, 0, stream>>>((const int4*)dstp, deg);
    k_scan<<<1, 1024, 0, stream>>>(deg, base, cursor);

    // node transform (independent of edge pass) + fused edge pass
    k_node<128><<<NB, 256, 0, stream>>>(x, W1, atts1, attd1, hbuf, asb, adb);
    k_edges<<<EDGE_BLOCKS, 256, 0, stream>>>(srcp, dstp, ea, smallf, cursor, rec, partials);
    k_prep2<<<1, 256, 0, stream>>>(smallf, partials);

    // ---- layer 1 aggregate ----
    k_agg<1><<<NB, 256, 0, stream>>>(rec, base, hbuf, asb, adb, smallf + 160, b1, obuf);

    // ---- layer 2 ----
    k_node<64><<<NB, 256, 0, stream>>>(obuf, W2, atts2, attd2, hbuf, asb, adb);
    k_agg<2><<<NB, 256, 0, stream>>>(rec, base, hbuf, asb, adb, smallf + 164, b2, obuf);

    // ---- head ----
    k_head<<<HB, 256, 0, stream>>>(obuf, lw1, lb1, lw2, lb2, outp);
}

// Round 3
// 598.362 us; speedup vs baseline: 1.2306x; 1.0509x over previous
//
#include <hip/hip_runtime.h>

#define N_NODES 50000
#define E_EDGES 1600000
#define NEG 0.2f
#define EDGE_BLOCKS 2048

__device__ __forceinline__ float lrelu(float x){ return x > 0.f ? x : NEG*x; }
__device__ __forceinline__ float bcastlane(float v, int k){
    return __int_as_float(__builtin_amdgcn_readlane(__float_as_int(v), k));
}
__device__ __forceinline__ unsigned bf16rn(float x){
    unsigned u = __float_as_uint(x);
    return (u + 0x7FFFu + ((u >> 16) & 1u)) >> 16;
}
__device__ __forceinline__ float bf2f(unsigned short u){
    return __uint_as_float(((unsigned)u) << 16);
}

// small[] layout (floats): [16..32) mean, [32..96) WeAtt1[k*4+h], [96..160) WeAtt2,
// [160..164) aeloop1, [164..168) aeloop2

__global__ void k_prep1(const float* __restrict__ We1, const float* __restrict__ atte1,
                        const float* __restrict__ We2, const float* __restrict__ atte2,
                        float* __restrict__ small){
    int t = threadIdx.x;            // 64 threads: t = k*4+h
    int k = t >> 2, hh = t & 3;
    float w1 = 0.f, w2 = 0.f;
    for (int c = 0; c < 16; ++c){
        w1 = fmaf(We1[k*64 + hh*16 + c], atte1[hh*16 + c], w1);
        w2 = fmaf(We2[k*64 + hh*16 + c], atte2[hh*16 + c], w2);
    }
    small[32 + t] = w1;
    small[96 + t] = w2;
}

__global__ __launch_bounds__(256) void k_hist(const int4* __restrict__ dst4, int* __restrict__ deg){
    int i = blockIdx.x*256 + threadIdx.x;
    if (i < E_EDGES/4){
        int4 v = dst4[i];
        atomicAdd(&deg[v.x], 1);
        atomicAdd(&deg[v.y], 1);
        atomicAdd(&deg[v.z], 1);
        atomicAdd(&deg[v.w], 1);
    }
}

__global__ __launch_bounds__(1024) void k_scan(const int* __restrict__ deg,
                                               int* __restrict__ base, int* __restrict__ cursor){
    __shared__ int part[1024];
    const int CH = (N_NODES + 1023)/1024;   // 49
    int t = threadIdx.x;
    int lo = t*CH;
    int hi = lo + CH; if (hi > N_NODES) hi = N_NODES;
    int s = 0;
    for (int i = lo; i < hi; ++i) s += deg[i];
    part[t] = s;
    __syncthreads();
    for (int off = 1; off < 1024; off <<= 1){
        int v = (t >= off) ? part[t-off] : 0;
        __syncthreads();
        part[t] += v;
        __syncthreads();
    }
    int ex = (t > 0) ? part[t-1] : 0;
    for (int i = lo; i < hi; ++i){ base[i] = ex; cursor[i] = ex; ex += deg[i]; }
    if (t == 0) base[N_NODES] = part[1023];
}

// Fused edge pass: ae1 (fp32) + ae2 (bf16) -> one scattered 32B record at CSR pos.
// Also reduces column sums of ea for the mean self-loop attr.
__global__ __launch_bounds__(256) void k_edges(const int* __restrict__ src, const int* __restrict__ dst,
                                               const float* __restrict__ ea, const float* __restrict__ small,
                                               int* __restrict__ cursor, float4* __restrict__ rec,
                                               float* __restrict__ partials){
    __shared__ float w1[64], w2[64];
    __shared__ float red[64];
    if (threadIdx.x < 64){ w1[threadIdx.x] = small[32+threadIdx.x]; w2[threadIdx.x] = small[96+threadIdx.x]; }
    __syncthreads();
    float cs[16];
#pragma unroll
    for (int k = 0; k < 16; ++k) cs[k] = 0.f;
    int stride = gridDim.x*blockDim.x;
    for (int e = blockIdx.x*blockDim.x + threadIdx.x; e < E_EDGES; e += stride){
        const float4* eap = (const float4*)(ea + (size_t)e*16);
        float ae1[4] = {0,0,0,0}, ae2[4] = {0,0,0,0};
#pragma unroll
        for (int q = 0; q < 4; ++q){
            float4 v4 = eap[q];
            float vv[4] = {v4.x, v4.y, v4.z, v4.w};
#pragma unroll
            for (int r = 0; r < 4; ++r){
                int k = q*4 + r;
                float xv = vv[r];
                cs[k] += xv;
#pragma unroll
                for (int hh = 0; hh < 4; ++hh){
                    ae1[hh] = fmaf(xv, w1[k*4+hh], ae1[hh]);
                    ae2[hh] = fmaf(xv, w2[k*4+hh], ae2[hh]);
                }
            }
        }
        int s = src[e], d = dst[e];
        int p = atomicAdd(&cursor[d], 1);
        unsigned pk01 = bf16rn(ae2[0]) | (bf16rn(ae2[1]) << 16);
        unsigned pk23 = bf16rn(ae2[2]) | (bf16rn(ae2[3]) << 16);
        float4 r0, r1;
        r0.x = __int_as_float(s); r0.y = ae1[0]; r0.z = ae1[1]; r0.w = ae1[2];
        r1.x = ae1[3]; r1.y = __uint_as_float(pk01); r1.z = __uint_as_float(pk23); r1.w = 0.f;
        rec[(size_t)p*2]     = r0;
        rec[(size_t)p*2 + 1] = r1;
    }
#pragma unroll
    for (int k = 0; k < 16; ++k){
        float v = cs[k];
        v += __shfl_xor(v,1); v += __shfl_xor(v,2); v += __shfl_xor(v,4);
        v += __shfl_xor(v,8); v += __shfl_xor(v,16); v += __shfl_xor(v,32);
        if ((threadIdx.x & 63) == 0) red[k*4 + (threadIdx.x>>6)] = v;
    }
    __syncthreads();
    if (threadIdx.x < 16){
        float v = red[threadIdx.x*4] + red[threadIdx.x*4+1] + red[threadIdx.x*4+2] + red[threadIdx.x*4+3];
        partials[blockIdx.x*16 + threadIdx.x] = v;
    }
}

__global__ __launch_bounds__(256) void k_prep2(float* __restrict__ small, const float* __restrict__ partials){
    __shared__ float sm[256];
    __shared__ float mean_s[16];
    int t = threadIdx.x;
    float v = 0.f;
    for (int r = (t>>4); r < EDGE_BLOCKS; r += 16) v += partials[r*16 + (t&15)];
    sm[t] = v;
    __syncthreads();
    if (t < 16){
        float s = 0.f;
#pragma unroll
        for (int i = 0; i < 16; ++i) s += sm[t + 16*i];
        float m = s * (1.0f/(float)E_EDGES);
        mean_s[t] = m; small[16+t] = m;
    }
    __syncthreads();
    if (t < 4){
        float a1 = 0.f, a2 = 0.f;
#pragma unroll
        for (int k = 0; k < 16; ++k){
            a1 = fmaf(mean_s[k], small[32 + k*4 + t], a1);
            a2 = fmaf(mean_s[k], small[96 + k*4 + t], a2);
        }
        small[160+t] = a1; small[164+t] = a2;
    }
}

// h = in @ W  (N x FIN @ FIN x 64) -> bf16 gather table; a_s/a_d per (node, head).
template<int FIN>
__global__ __launch_bounds__(256) void k_node(const float* __restrict__ in, const float* __restrict__ W,
                                              const float* __restrict__ att_s, const float* __restrict__ att_d,
                                              unsigned short* __restrict__ hb, float* __restrict__ a_s,
                                              float* __restrict__ a_d){
    __shared__ float Wl[FIN*64];
    for (int i = threadIdx.x; i < FIN*64; i += 256) Wl[i] = W[i];
    __syncthreads();
    int lane = threadIdx.x & 63;
    int node = blockIdx.x*4 + (threadIdx.x >> 6);   // N % 4 == 0, always valid
    const float* row = in + (size_t)node*FIN;
    float x0 = row[lane];
    float x1 = 0.f;
    if constexpr (FIN == 128) x1 = row[64 + lane];
    float acc = 0.f;
#pragma unroll
    for (int k = 0; k < 64; ++k)
        acc = fmaf(bcastlane(x0, k), Wl[k*64 + lane], acc);
    if constexpr (FIN == 128){
#pragma unroll
        for (int k = 0; k < 64; ++k)
            acc = fmaf(bcastlane(x1, k), Wl[(64+k)*64 + lane], acc);
    }
    hb[(size_t)node*64 + lane] = (unsigned short)bf16rn(acc);
    float ps = acc * att_s[lane];
    float pd = acc * att_d[lane];
    ps += __shfl_xor(ps,1); ps += __shfl_xor(ps,2); ps += __shfl_xor(ps,4); ps += __shfl_xor(ps,8);
    pd += __shfl_xor(pd,1); pd += __shfl_xor(pd,2); pd += __shfl_xor(pd,4); pd += __shfl_xor(pd,8);
    if ((lane & 15) == 0){
        a_s[node*4 + (lane>>4)] = ps;
        a_d[node*4 + (lane>>4)] = pd;
    }
}

template<int L>
__device__ __forceinline__ float ae_sel(const float4& r0, const float4& r1, int hh){
    if constexpr (L == 1){
        return (hh == 0) ? r0.y : (hh == 1) ? r0.z : (hh == 2) ? r0.w : r1.x;
    } else {
        unsigned pk = __float_as_uint((hh < 2) ? r1.y : r1.z);
        return __uint_as_float((hh & 1) ? (pk & 0xFFFF0000u) : (pk << 16));
    }
}

// One wave per node, lane = head*16+chan. No-max softmax (alphas bounded ~|1|),
// 2-way unrolled independent accumulators, bf16 h gather.
template<int L>
__global__ __launch_bounds__(256) void k_agg(const float4* __restrict__ rec, const int* __restrict__ base,
                                             const unsigned short* __restrict__ hb,
                                             const float* __restrict__ a_s, const float* __restrict__ a_d,
                                             const float* __restrict__ aeloop, const float* __restrict__ bias,
                                             float* __restrict__ out){
    int lane = threadIdx.x & 63;
    int n = blockIdx.x*4 + (threadIdx.x >> 6);
    int hh = lane >> 4;
    float ad_v = a_d[n*4+hh];
    float wL = __expf(lrelu(a_s[n*4+hh] + ad_v + aeloop[hh]));
    float s0 = wL, s1 = 0.f;
    float acc0 = wL * bf2f(hb[(size_t)n*64 + lane]), acc1 = 0.f;
    int b0 = base[n], b1 = base[n+1];
    int p = b0;
    for (; p + 2 <= b1; p += 2){
        float4 rA0 = rec[(size_t)p*2],   rA1 = rec[(size_t)p*2+1];
        float4 rB0 = rec[(size_t)p*2+2], rB1 = rec[(size_t)p*2+3];
        int siA = __float_as_int(rA0.x), siB = __float_as_int(rB0.x);
        float hvA = bf2f(hb[(size_t)siA*64 + lane]);
        float hvB = bf2f(hb[(size_t)siB*64 + lane]);
        float asA = a_s[siA*4 + hh];
        float asB = a_s[siB*4 + hh];
        float wA = __expf(lrelu(asA + ad_v + ae_sel<L>(rA0, rA1, hh)));
        float wB = __expf(lrelu(asB + ad_v + ae_sel<L>(rB0, rB1, hh)));
        s0 += wA; acc0 = fmaf(wA, hvA, acc0);
        s1 += wB; acc1 = fmaf(wB, hvB, acc1);
    }
    if (p < b1){
        float4 r0 = rec[(size_t)p*2], r1 = rec[(size_t)p*2+1];
        int si = __float_as_int(r0.x);
        float hv = bf2f(hb[(size_t)si*64 + lane]);
        float as_v = a_s[si*4 + hh];
        float w = __expf(lrelu(as_v + ad_v + ae_sel<L>(r0, r1, hh)));
        s1 += w; acc1 = fmaf(w, hv, acc1);
    }
    float s = s0 + s1;
    float val = (acc0 + acc1) / (s + 1e-16f) + bias[lane];
    out[(size_t)n*64 + lane] = fmaxf(val, 0.f);
}

__global__ __launch_bounds__(256) void k_head(const float* __restrict__ h2,
                                              const float* __restrict__ lw1, const float* __restrict__ lb1,
                                              const float* __restrict__ lw2, const float* __restrict__ lb2,
                                              float* __restrict__ out){
    int n = blockIdx.x*256 + threadIdx.x;
    if (n >= N_NODES) return;
    float y16[16];
#pragma unroll
    for (int j = 0; j < 16; ++j) y16[j] = lb1[j];
    const float4* hp = (const float4*)(h2 + (size_t)n*64);
#pragma unroll
    for (int k4 = 0; k4 < 16; ++k4){
        float4 hv = hp[k4];
        float hvv[4] = {hv.x, hv.y, hv.z, hv.w};
#pragma unroll
        for (int r = 0; r < 4; ++r){
            float x = hvv[r];
            int k = k4*4 + r;
#pragma unroll
            for (int j = 0; j < 16; ++j) y16[j] = fmaf(x, lw1[k*16+j], y16[j]);
        }
    }
    float y[40];
#pragma unroll
    for (int o = 0; o < 40; ++o) y[o] = lb2[o];
#pragma unroll
    for (int j = 0; j < 16; ++j){
        float x = y16[j];
#pragma unroll
        for (int o = 0; o < 40; ++o) y[o] = fmaf(x, lw2[j*40+o], y[o]);
    }
    float mx = y[0];
#pragma unroll
    for (int o = 1; o < 40; ++o) mx = fmaxf(mx, y[o]);
    float sum = 0.f;
#pragma unroll
    for (int o = 0; o < 40; ++o) sum += __expf(y[o] - mx);
    float ls = __logf(sum) + mx;
    float* op = out + (size_t)n*40;
#pragma unroll
    for (int o = 0; o < 40; ++o) op[o] = y[o] - ls;
}

extern "C" void kernel_launch(void* const* d_in, const int* in_sizes, int n_in,
                              void* d_out, int out_size, void* d_ws, size_t ws_size,
                              hipStream_t stream){
    const float* x     = (const float*)d_in[0];
    const int*   ei    = (const int*)  d_in[1];
    const float* ea    = (const float*)d_in[2];
    const float* W1    = (const float*)d_in[3];
    const float* atts1 = (const float*)d_in[4];
    const float* attd1 = (const float*)d_in[5];
    const float* We1   = (const float*)d_in[6];
    const float* atte1 = (const float*)d_in[7];
    const float* b1    = (const float*)d_in[8];
    const float* W2    = (const float*)d_in[9];
    const float* atts2 = (const float*)d_in[10];
    const float* attd2 = (const float*)d_in[11];
    const float* We2   = (const float*)d_in[12];
    const float* atte2 = (const float*)d_in[13];
    const float* b2    = (const float*)d_in[14];
    const float* lw1   = (const float*)d_in[15];
    const float* lb1   = (const float*)d_in[16];
    const float* lw2   = (const float*)d_in[17];
    const float* lb2   = (const float*)d_in[18];
    float* outp = (float*)d_out;

    const int* srcp = ei;
    const int* dstp = ei + E_EDGES;

    char* ws = (char*)d_ws;
    size_t off = 0;
    auto alloc = [&](size_t bytes) -> void* {
        void* p = ws + off;
        off = (off + bytes + 255) & ~(size_t)255;
        return p;
    };
    float*  smallf   = (float*) alloc(256*sizeof(float));
    float*  partials = (float*) alloc((size_t)EDGE_BLOCKS*16*sizeof(float));
    int*    deg      = (int*)   alloc((size_t)N_NODES*sizeof(int));
    int*    base     = (int*)   alloc((size_t)(N_NODES+1)*sizeof(int));
    int*    cursor   = (int*)   alloc((size_t)N_NODES*sizeof(int));
    float4* rec      = (float4*)alloc((size_t)E_EDGES*32);
    unsigned short* hb = (unsigned short*)alloc((size_t)N_NODES*64*sizeof(unsigned short));
    float*  obuf     = (float*) alloc((size_t)N_NODES*64*sizeof(float));
    float*  asb      = (float*) alloc((size_t)N_NODES*4*sizeof(float));
    float*  adb      = (float*) alloc((size_t)N_NODES*4*sizeof(float));

    const int NB = N_NODES/4;             // 12500
    const int HB = (N_NODES + 255)/256;   // 196

    hipMemsetAsync(deg, 0, (size_t)N_NODES*sizeof(int), stream);
    k_prep1<<<1, 64, 0, stream>>>(We1, atte1, We2, atte2, smallf);
    k_hist<<<(E_EDGES/4 + 255)/256, 256, 0, stream>>>((const int4*)dstp, deg);
    k_scan<<<1, 1024, 0, stream>>>(deg, base, cursor);

    // node transform (independent of edge pass) + fused edge pass
    k_node<128><<<NB, 256, 0, stream>>>(x, W1, atts1, attd1, hb, asb, adb);
    k_edges<<<EDGE_BLOCKS, 256, 0, stream>>>(srcp, dstp, ea, smallf, cursor, rec, partials);
    k_prep2<<<1, 256, 0, stream>>>(smallf, partials);

    // ---- layer 1 aggregate ----
    k_agg<1><<<NB, 256, 0, stream>>>(rec, base, hb, asb, adb, smallf + 160, b1, obuf);

    // ---- layer 2 ----
    k_node<64><<<NB, 256, 0, stream>>>(obuf, W2, atts2, attd2, hb, asb, adb);
    k_agg<2><<<NB, 256, 0, stream>>>(rec, base, hb, asb, adb, smallf + 164, b2, obuf);

    // ---- head ----
    k_head<<<HB, 256, 0, stream>>>(obuf, lw1, lb1, lw2, lb2, outp);
}

// Round 4
// 495.966 us; speedup vs baseline: 1.4846x; 1.2065x over previous
//
#include <hip/hip_runtime.h>

#define N_NODES 50000
#define E_EDGES 1600000
#define NEG 0.2f
#define EDGE_BLOCKS 2048
#define SCAN_BLOCKS ((N_NODES + 255)/256)   // 196

__device__ __forceinline__ float lrelu(float x){ return x > 0.f ? x : NEG*x; }
__device__ __forceinline__ float bcastlane(float v, int k){
    return __int_as_float(__builtin_amdgcn_readlane(__float_as_int(v), k));
}
__device__ __forceinline__ unsigned bf16rn(float x){
    unsigned u = __float_as_uint(x);
    return (u + 0x7FFFu + ((u >> 16) & 1u)) >> 16;
}
__device__ __forceinline__ float bf2f(unsigned short u){
    return __uint_as_float(((unsigned)u) << 16);
}

// small[] layout (floats): [16..32) mean, [32..96) WeAtt1[k*4+h], [96..160) WeAtt2,
// [160..164) aeloop1, [164..168) aeloop2

__global__ void k_prep1(const float* __restrict__ We1, const float* __restrict__ atte1,
                        const float* __restrict__ We2, const float* __restrict__ atte2,
                        float* __restrict__ small){
    int t = threadIdx.x;            // 64 threads: t = k*4+h
    int k = t >> 2, hh = t & 3;
    float w1 = 0.f, w2 = 0.f;
    for (int c = 0; c < 16; ++c){
        w1 = fmaf(We1[k*64 + hh*16 + c], atte1[hh*16 + c], w1);
        w2 = fmaf(We2[k*64 + hh*16 + c], atte2[hh*16 + c], w2);
    }
    small[32 + t] = w1;
    small[96 + t] = w2;
}

__global__ __launch_bounds__(256) void k_hist(const int4* __restrict__ dst4, int* __restrict__ deg){
    int i = blockIdx.x*256 + threadIdx.x;
    if (i < E_EDGES/4){
        int4 v = dst4[i];
        atomicAdd(&deg[v.x], 1);
        atomicAdd(&deg[v.y], 1);
        atomicAdd(&deg[v.z], 1);
        atomicAdd(&deg[v.w], 1);
    }
}

// ---- hierarchical scan ----
__global__ __launch_bounds__(256) void k_scan_a(const int* __restrict__ deg, int* __restrict__ bsum){
    int i = blockIdx.x*256 + threadIdx.x;
    int v = (i < N_NODES) ? deg[i] : 0;
    v += __shfl_xor(v,1); v += __shfl_xor(v,2); v += __shfl_xor(v,4);
    v += __shfl_xor(v,8); v += __shfl_xor(v,16); v += __shfl_xor(v,32);
    __shared__ int ws[4];
    if ((threadIdx.x & 63) == 0) ws[threadIdx.x >> 6] = v;
    __syncthreads();
    if (threadIdx.x == 0) bsum[blockIdx.x] = ws[0] + ws[1] + ws[2] + ws[3];
}

__global__ __launch_bounds__(256) void k_scan_b(const int* __restrict__ bsum, int* __restrict__ boff){
    __shared__ int sm[256];
    int t = threadIdx.x;
    int v = (t < SCAN_BLOCKS) ? bsum[t] : 0;
    sm[t] = v;
    __syncthreads();
    for (int off = 1; off < 256; off <<= 1){
        int u = (t >= off) ? sm[t-off] : 0;
        __syncthreads();
        sm[t] += u;
        __syncthreads();
    }
    // exclusive offsets
    boff[t] = (t > 0) ? sm[t-1] : 0;
    if (t == 0) boff[SCAN_BLOCKS] = sm[255];   // grand total (=E)
}

__global__ __launch_bounds__(256) void k_scan_c(const int* __restrict__ deg, const int* __restrict__ boff,
                                                int* __restrict__ base, int* __restrict__ cursor){
    int i = blockIdx.x*256 + threadIdx.x;
    int lane = threadIdx.x & 63, wid = threadIdx.x >> 6;
    int v = (i < N_NODES) ? deg[i] : 0;
    int inc = v;
    for (int off = 1; off < 64; off <<= 1){
        int u = __shfl_up(inc, off);
        if (lane >= off) inc += u;
    }
    __shared__ int wsum[4];
    if (lane == 63) wsum[wid] = inc;
    __syncthreads();
    int wpre = 0;
#pragma unroll
    for (int w = 0; w < 4; ++w) wpre += (w < wid) ? wsum[w] : 0;
    int ex = boff[blockIdx.x] + wpre + inc - v;
    if (i < N_NODES){ base[i] = ex; cursor[i] = ex; }
    if (i == N_NODES - 1) base[N_NODES] = ex + v;
}

// Fused edge pass: ae1 (fp32) + ae2 (bf16) -> one scattered 32B record at CSR pos.
// Also reduces column sums of ea for the mean self-loop attr.
__global__ __launch_bounds__(256) void k_edges(const int* __restrict__ src, const int* __restrict__ dst,
                                               const float* __restrict__ ea, const float* __restrict__ small,
                                               int* __restrict__ cursor, float4* __restrict__ rec,
                                               float* __restrict__ partials){
    __shared__ float w1[64], w2[64];
    __shared__ float red[64];
    if (threadIdx.x < 64){ w1[threadIdx.x] = small[32+threadIdx.x]; w2[threadIdx.x] = small[96+threadIdx.x]; }
    __syncthreads();
    float cs[16];
#pragma unroll
    for (int k = 0; k < 16; ++k) cs[k] = 0.f;
    int stride = gridDim.x*blockDim.x;
    for (int e = blockIdx.x*blockDim.x + threadIdx.x; e < E_EDGES; e += stride){
        const float4* eap = (const float4*)(ea + (size_t)e*16);
        float ae1[4] = {0,0,0,0}, ae2[4] = {0,0,0,0};
#pragma unroll
        for (int q = 0; q < 4; ++q){
            float4 v4 = eap[q];
            float vv[4] = {v4.x, v4.y, v4.z, v4.w};
#pragma unroll
            for (int r = 0; r < 4; ++r){
                int k = q*4 + r;
                float xv = vv[r];
                cs[k] += xv;
#pragma unroll
                for (int hh = 0; hh < 4; ++hh){
                    ae1[hh] = fmaf(xv, w1[k*4+hh], ae1[hh]);
                    ae2[hh] = fmaf(xv, w2[k*4+hh], ae2[hh]);
                }
            }
        }
        int s = src[e], d = dst[e];
        int p = atomicAdd(&cursor[d], 1);
        unsigned pk01 = bf16rn(ae2[0]) | (bf16rn(ae2[1]) << 16);
        unsigned pk23 = bf16rn(ae2[2]) | (bf16rn(ae2[3]) << 16);
        float4 r0, r1;
        r0.x = __int_as_float(s); r0.y = ae1[0]; r0.z = ae1[1]; r0.w = ae1[2];
        r1.x = ae1[3]; r1.y = __uint_as_float(pk01); r1.z = __uint_as_float(pk23); r1.w = 0.f;
        rec[(size_t)p*2]     = r0;
        rec[(size_t)p*2 + 1] = r1;
    }
#pragma unroll
    for (int k = 0; k < 16; ++k){
        float v = cs[k];
        v += __shfl_xor(v,1); v += __shfl_xor(v,2); v += __shfl_xor(v,4);
        v += __shfl_xor(v,8); v += __shfl_xor(v,16); v += __shfl_xor(v,32);
        if ((threadIdx.x & 63) == 0) red[k*4 + (threadIdx.x>>6)] = v;
    }
    __syncthreads();
    if (threadIdx.x < 16){
        float v = red[threadIdx.x*4] + red[threadIdx.x*4+1] + red[threadIdx.x*4+2] + red[threadIdx.x*4+3];
        partials[blockIdx.x*16 + threadIdx.x] = v;
    }
}

__global__ __launch_bounds__(256) void k_prep2(float* __restrict__ small, const float* __restrict__ partials){
    __shared__ float sm[256];
    __shared__ float mean_s[16];
    int t = threadIdx.x;
    float v = 0.f;
    for (int r = (t>>4); r < EDGE_BLOCKS; r += 16) v += partials[r*16 + (t&15)];
    sm[t] = v;
    __syncthreads();
    if (t < 16){
        float s = 0.f;
#pragma unroll
        for (int i = 0; i < 16; ++i) s += sm[t + 16*i];
        float m = s * (1.0f/(float)E_EDGES);
        mean_s[t] = m; small[16+t] = m;
    }
    __syncthreads();
    if (t < 4){
        float a1 = 0.f, a2 = 0.f;
#pragma unroll
        for (int k = 0; k < 16; ++k){
            a1 = fmaf(mean_s[k], small[32 + k*4 + t], a1);
            a2 = fmaf(mean_s[k], small[96 + k*4 + t], a2);
        }
        small[160+t] = a1; small[164+t] = a2;
    }
}

// h = in @ W  (N x FIN @ FIN x 64) -> bf16 gather table; a_s/a_d per (node, head).
template<int FIN>
__global__ __launch_bounds__(256) void k_node(const float* __restrict__ in, const float* __restrict__ W,
                                              const float* __restrict__ att_s, const float* __restrict__ att_d,
                                              unsigned short* __restrict__ hb, float* __restrict__ a_s,
                                              float* __restrict__ a_d){
    __shared__ float Wl[FIN*64];
    for (int i = threadIdx.x; i < FIN*64; i += 256) Wl[i] = W[i];
    __syncthreads();
    int lane = threadIdx.x & 63;
    int node = blockIdx.x*4 + (threadIdx.x >> 6);   // N % 4 == 0, always valid
    const float* row = in + (size_t)node*FIN;
    float x0 = row[lane];
    float x1 = 0.f;
    if constexpr (FIN == 128) x1 = row[64 + lane];
    float acc = 0.f;
#pragma unroll
    for (int k = 0; k < 64; ++k)
        acc = fmaf(bcastlane(x0, k), Wl[k*64 + lane], acc);
    if constexpr (FIN == 128){
#pragma unroll
        for (int k = 0; k < 64; ++k)
            acc = fmaf(bcastlane(x1, k), Wl[(64+k)*64 + lane], acc);
    }
    hb[(size_t)node*64 + lane] = (unsigned short)bf16rn(acc);
    float ps = acc * att_s[lane];
    float pd = acc * att_d[lane];
    ps += __shfl_xor(ps,1); ps += __shfl_xor(ps,2); ps += __shfl_xor(ps,4); ps += __shfl_xor(ps,8);
    pd += __shfl_xor(pd,1); pd += __shfl_xor(pd,2); pd += __shfl_xor(pd,4); pd += __shfl_xor(pd,8);
    if ((lane & 15) == 0){
        a_s[node*4 + (lane>>4)] = ps;
        a_d[node*4 + (lane>>4)] = pd;
    }
}

template<int L>
__device__ __forceinline__ float ae_sel(const float4& r0, const float4& r1, int hh){
    if constexpr (L == 1){
        return (hh == 0) ? r0.y : (hh == 1) ? r0.z : (hh == 2) ? r0.w : r1.x;
    } else {
        unsigned pk = __float_as_uint((hh < 2) ? r1.y : r1.z);
        return __uint_as_float((hh & 1) ? (pk & 0xFFFF0000u) : (pk << 16));
    }
}

// One wave per node, lane = head*16+chan. No-max softmax (alphas bounded ~|1|),
// 2-way unrolled independent accumulators, bf16 h gather.
template<int L>
__global__ __launch_bounds__(256) void k_agg(const float4* __restrict__ rec, const int* __restrict__ base,
                                             const unsigned short* __restrict__ hb,
                                             const float* __restrict__ a_s, const float* __restrict__ a_d,
                                             const float* __restrict__ aeloop, const float* __restrict__ bias,
                                             float* __restrict__ out){
    int lane = threadIdx.x & 63;
    int n = blockIdx.x*4 + (threadIdx.x >> 6);
    int hh = lane >> 4;
    float ad_v = a_d[n*4+hh];
    float wL = __expf(lrelu(a_s[n*4+hh] + ad_v + aeloop[hh]));
    float s0 = wL, s1 = 0.f;
    float acc0 = wL * bf2f(hb[(size_t)n*64 + lane]), acc1 = 0.f;
    int b0 = base[n], b1 = base[n+1];
    int p = b0;
    for (; p + 2 <= b1; p += 2){
        float4 rA0 = rec[(size_t)p*2],   rA1 = rec[(size_t)p*2+1];
        float4 rB0 = rec[(size_t)p*2+2], rB1 = rec[(size_t)p*2+3];
        int siA = __float_as_int(rA0.x), siB = __float_as_int(rB0.x);
        float hvA = bf2f(hb[(size_t)siA*64 + lane]);
        float hvB = bf2f(hb[(size_t)siB*64 + lane]);
        float asA = a_s[siA*4 + hh];
        float asB = a_s[siB*4 + hh];
        float wA = __expf(lrelu(asA + ad_v + ae_sel<L>(rA0, rA1, hh)));
        float wB = __expf(lrelu(asB + ad_v + ae_sel<L>(rB0, rB1, hh)));
        s0 += wA; acc0 = fmaf(wA, hvA, acc0);
        s1 += wB; acc1 = fmaf(wB, hvB, acc1);
    }
    if (p < b1){
        float4 r0 = rec[(size_t)p*2], r1 = rec[(size_t)p*2+1];
        int si = __float_as_int(r0.x);
        float hv = bf2f(hb[(size_t)si*64 + lane]);
        float as_v = a_s[si*4 + hh];
        float w = __expf(lrelu(as_v + ad_v + ae_sel<L>(r0, r1, hh)));
        s1 += w; acc1 = fmaf(w, hv, acc1);
    }
    float s = s0 + s1;
    float val = (acc0 + acc1) / (s + 1e-16f) + bias[lane];
    out[(size_t)n*64 + lane] = fmaxf(val, 0.f);
}

__global__ __launch_bounds__(256) void k_head(const float* __restrict__ h2,
                                              const float* __restrict__ lw1, const float* __restrict__ lb1,
                                              const float* __restrict__ lw2, const float* __restrict__ lb2,
                                              float* __restrict__ out){
    int n = blockIdx.x*256 + threadIdx.x;
    if (n >= N_NODES) return;
    float y16[16];
#pragma unroll
    for (int j = 0; j < 16; ++j) y16[j] = lb1[j];
    const float4* hp = (const float4*)(h2 + (size_t)n*64);
#pragma unroll
    for (int k4 = 0; k4 < 16; ++k4){
        float4 hv = hp[k4];
        float hvv[4] = {hv.x, hv.y, hv.z, hv.w};
#pragma unroll
        for (int r = 0; r < 4; ++r){
            float x = hvv[r];
            int k = k4*4 + r;
#pragma unroll
            for (int j = 0; j < 16; ++j) y16[j] = fmaf(x, lw1[k*16+j], y16[j]);
        }
    }
    float y[40];
#pragma unroll
    for (int o = 0; o < 40; ++o) y[o] = lb2[o];
#pragma unroll
    for (int j = 0; j < 16; ++j){
        float x = y16[j];
#pragma unroll
        for (int o = 0; o < 40; ++o) y[o] = fmaf(x, lw2[j*40+o], y[o]);
    }
    float mx = y[0];
#pragma unroll
    for (int o = 1; o < 40; ++o) mx = fmaxf(mx, y[o]);
    float sum = 0.f;
#pragma unroll
    for (int o = 0; o < 40; ++o) sum += __expf(y[o] - mx);
    float ls = __logf(sum) + mx;
    float* op = out + (size_t)n*40;
#pragma unroll
    for (int o = 0; o < 40; ++o) op[o] = y[o] - ls;
}

extern "C" void kernel_launch(void* const* d_in, const int* in_sizes, int n_in,
                              void* d_out, int out_size, void* d_ws, size_t ws_size,
                              hipStream_t stream){
    const float* x     = (const float*)d_in[0];
    const int*   ei    = (const int*)  d_in[1];
    const float* ea    = (const float*)d_in[2];
    const float* W1    = (const float*)d_in[3];
    const float* atts1 = (const float*)d_in[4];
    const float* attd1 = (const float*)d_in[5];
    const float* We1   = (const float*)d_in[6];
    const float* atte1 = (const float*)d_in[7];
    const float* b1    = (const float*)d_in[8];
    const float* W2    = (const float*)d_in[9];
    const float* atts2 = (const float*)d_in[10];
    const float* attd2 = (const float*)d_in[11];
    const float* We2   = (const float*)d_in[12];
    const float* atte2 = (const float*)d_in[13];
    const float* b2    = (const float*)d_in[14];
    const float* lw1   = (const float*)d_in[15];
    const float* lb1   = (const float*)d_in[16];
    const float* lw2   = (const float*)d_in[17];
    const float* lb2   = (const float*)d_in[18];
    float* outp = (float*)d_out;

    const int* srcp = ei;
    const int* dstp = ei + E_EDGES;

    char* ws = (char*)d_ws;
    size_t off = 0;
    auto alloc = [&](size_t bytes) -> void* {
        void* p = ws + off;
        off = (off + bytes + 255) & ~(size_t)255;
        return p;
    };
    float*  smallf   = (float*) alloc(256*sizeof(float));
    float*  partials = (float*) alloc((size_t)EDGE_BLOCKS*16*sizeof(float));
    int*    deg      = (int*)   alloc((size_t)N_NODES*sizeof(int));
    int*    base     = (int*)   alloc((size_t)(N_NODES+1)*sizeof(int));
    int*    cursor   = (int*)   alloc((size_t)N_NODES*sizeof(int));
    int*    bsum     = (int*)   alloc((size_t)(SCAN_BLOCKS+1)*sizeof(int));
    int*    boff     = (int*)   alloc((size_t)(SCAN_BLOCKS+1)*sizeof(int));
    float4* rec      = (float4*)alloc((size_t)E_EDGES*32);
    unsigned short* hb = (unsigned short*)alloc((size_t)N_NODES*64*sizeof(unsigned short));
    float*  obuf     = (float*) alloc((size_t)N_NODES*64*sizeof(float));
    float*  asb      = (float*) alloc((size_t)N_NODES*4*sizeof(float));
    float*  adb      = (float*) alloc((size_t)N_NODES*4*sizeof(float));

    const int NB = N_NODES/4;             // 12500
    const int HB = (N_NODES + 255)/256;   // 196

    hipMemsetAsync(deg, 0, (size_t)N_NODES*sizeof(int), stream);
    k_prep1<<<1, 64, 0, stream>>>(We1, atte1, We2, atte2, smallf);
    k_hist<<<(E_EDGES/4 + 255)/256, 256, 0, stream>>>((const int4*)dstp, deg);
    k_scan_a<<<SCAN_BLOCKS, 256, 0, stream>>>(deg, bsum);
    k_scan_b<<<1, 256, 0, stream>>>(bsum, boff);
    k_scan_c<<<SCAN_BLOCKS, 256, 0, stream>>>(deg, boff, base, cursor);

    // node transform (independent of edge pass) + fused edge pass
    k_node<128><<<NB, 256, 0, stream>>>(x, W1, atts1, attd1, hb, asb, adb);
    k_edges<<<EDGE_BLOCKS, 256, 0, stream>>>(srcp, dstp, ea, smallf, cursor, rec, partials);
    k_prep2<<<1, 256, 0, stream>>>(smallf, partials);

    // ---- layer 1 aggregate ----
    k_agg<1><<<NB, 256, 0, stream>>>(rec, base, hb, asb, adb, smallf + 160, b1, obuf);

    // ---- layer 2 ----
    k_node<64><<<NB, 256, 0, stream>>>(obuf, W2, atts2, attd2, hb, asb, adb);
    k_agg<2><<<NB, 256, 0, stream>>>(rec, base, hb, asb, adb, smallf + 164, b2, obuf);

    // ---- head ----
    k_head<<<HB, 256, 0, stream>>>(obuf, lw1, lb1, lw2, lb2, outp);
}

// Round 5
// 485.595 us; speedup vs baseline: 1.5163x; 1.0214x over previous
//
#include <hip/hip_runtime.h>

#define N_NODES 50000
#define E_EDGES 1600000
#define NEG 0.2f
#define EDGE_BLOCKS 2048
#define SCAN_BLOCKS ((N_NODES + 255)/256)   // 196

__device__ __forceinline__ float lrelu(float x){ return x > 0.f ? x : NEG*x; }
__device__ __forceinline__ float bcastlane(float v, int k){
    return __int_as_float(__builtin_amdgcn_readlane(__float_as_int(v), k));
}
__device__ __forceinline__ unsigned bf16rn(float x){
    unsigned u = __float_as_uint(x);
    return (u + 0x7FFFu + ((u >> 16) & 1u)) >> 16;
}
__device__ __forceinline__ float bf2f(unsigned short u){
    return __uint_as_float(((unsigned)u) << 16);
}
// unpack one bf16 half of a packed dword: hi ? high16 : low16
__device__ __forceinline__ float bfsel(unsigned pk, int hi){
    return __uint_as_float(hi ? (pk & 0xFFFF0000u) : (pk << 16));
}

// small[] layout (floats): [16..32) mean, [32..96) WeAtt1[k*4+h], [96..160) WeAtt2,
// [160..164) aeloop1, [164..168) aeloop2

__global__ void k_prep1(const float* __restrict__ We1, const float* __restrict__ atte1,
                        const float* __restrict__ We2, const float* __restrict__ atte2,
                        float* __restrict__ small){
    int t = threadIdx.x;            // 64 threads: t = k*4+h
    int k = t >> 2, hh = t & 3;
    float w1 = 0.f, w2 = 0.f;
    for (int c = 0; c < 16; ++c){
        w1 = fmaf(We1[k*64 + hh*16 + c], atte1[hh*16 + c], w1);
        w2 = fmaf(We2[k*64 + hh*16 + c], atte2[hh*16 + c], w2);
    }
    small[32 + t] = w1;
    small[96 + t] = w2;
}

__global__ __launch_bounds__(256) void k_hist(const int4* __restrict__ dst4, int* __restrict__ deg){
    int i = blockIdx.x*256 + threadIdx.x;
    if (i < E_EDGES/4){
        int4 v = dst4[i];
        atomicAdd(&deg[v.x], 1);
        atomicAdd(&deg[v.y], 1);
        atomicAdd(&deg[v.z], 1);
        atomicAdd(&deg[v.w], 1);
    }
}

// ---- hierarchical scan ----
__global__ __launch_bounds__(256) void k_scan_a(const int* __restrict__ deg, int* __restrict__ bsum){
    int i = blockIdx.x*256 + threadIdx.x;
    int v = (i < N_NODES) ? deg[i] : 0;
    v += __shfl_xor(v,1); v += __shfl_xor(v,2); v += __shfl_xor(v,4);
    v += __shfl_xor(v,8); v += __shfl_xor(v,16); v += __shfl_xor(v,32);
    __shared__ int ws[4];
    if ((threadIdx.x & 63) == 0) ws[threadIdx.x >> 6] = v;
    __syncthreads();
    if (threadIdx.x == 0) bsum[blockIdx.x] = ws[0] + ws[1] + ws[2] + ws[3];
}

__global__ __launch_bounds__(256) void k_scan_b(const int* __restrict__ bsum, int* __restrict__ boff){
    __shared__ int sm[256];
    int t = threadIdx.x;
    int v = (t < SCAN_BLOCKS) ? bsum[t] : 0;
    sm[t] = v;
    __syncthreads();
    for (int off = 1; off < 256; off <<= 1){
        int u = (t >= off) ? sm[t-off] : 0;
        __syncthreads();
        sm[t] += u;
        __syncthreads();
    }
    boff[t] = (t > 0) ? sm[t-1] : 0;
    if (t == 0) boff[SCAN_BLOCKS] = sm[255];
}

__global__ __launch_bounds__(256) void k_scan_c(const int* __restrict__ deg, const int* __restrict__ boff,
                                                int* __restrict__ base, int* __restrict__ cursor){
    int i = blockIdx.x*256 + threadIdx.x;
    int lane = threadIdx.x & 63, wid = threadIdx.x >> 6;
    int v = (i < N_NODES) ? deg[i] : 0;
    int inc = v;
    for (int off = 1; off < 64; off <<= 1){
        int u = __shfl_up(inc, off);
        if (lane >= off) inc += u;
    }
    __shared__ int wsum[4];
    if (lane == 63) wsum[wid] = inc;
    __syncthreads();
    int wpre = 0;
#pragma unroll
    for (int w = 0; w < 4; ++w) wpre += (w < wid) ? wsum[w] : 0;
    int ex = boff[blockIdx.x] + wpre + inc - v;
    if (i < N_NODES){ base[i] = ex; cursor[i] = ex; }
    if (i == N_NODES - 1) base[N_NODES] = ex + v;
}

// h = in @ W  (N x FIN @ FIN x 64) -> bf16 gather table; a_s/a_d per (node, head).
template<int FIN>
__global__ __launch_bounds__(256) void k_node(const float* __restrict__ in, const float* __restrict__ W,
                                              const float* __restrict__ att_s, const float* __restrict__ att_d,
                                              unsigned short* __restrict__ hb, float* __restrict__ a_s,
                                              float* __restrict__ a_d){
    __shared__ float Wl[FIN*64];
    for (int i = threadIdx.x; i < FIN*64; i += 256) Wl[i] = W[i];
    __syncthreads();
    int lane = threadIdx.x & 63;
    int node = blockIdx.x*4 + (threadIdx.x >> 6);
    const float* row = in + (size_t)node*FIN;
    float x0 = row[lane];
    float x1 = 0.f;
    if constexpr (FIN == 128) x1 = row[64 + lane];
    float acc = 0.f;
#pragma unroll
    for (int k = 0; k < 64; ++k)
        acc = fmaf(bcastlane(x0, k), Wl[k*64 + lane], acc);
    if constexpr (FIN == 128){
#pragma unroll
        for (int k = 0; k < 64; ++k)
            acc = fmaf(bcastlane(x1, k), Wl[(64+k)*64 + lane], acc);
    }
    hb[(size_t)node*64 + lane] = (unsigned short)bf16rn(acc);
    float ps = acc * att_s[lane];
    float pd = acc * att_d[lane];
    ps += __shfl_xor(ps,1); ps += __shfl_xor(ps,2); ps += __shfl_xor(ps,4); ps += __shfl_xor(ps,8);
    pd += __shfl_xor(pd,1); pd += __shfl_xor(pd,2); pd += __shfl_xor(pd,4); pd += __shfl_xor(pd,8);
    if ((lane & 15) == 0){
        a_s[node*4 + (lane>>4)] = ps;
        a_d[node*4 + (lane>>4)] = pd;
    }
}

// Fused edge pass: compute ae1, ae2, w1 = exp(lrelu(as1+ad1+ae1)), write ONE 32B
// scattered record: r0={si, w1pk01, w1pk23, d}, r1={ae2pk01, ae2pk23, 0, 0}.
// Also reduces column sums of ea for the mean self-loop attr.
__global__ __launch_bounds__(256) void k_edges(const int* __restrict__ src, const int* __restrict__ dst,
                                               const float* __restrict__ ea, const float* __restrict__ small,
                                               const float* __restrict__ a_s, const float* __restrict__ a_d,
                                               int* __restrict__ cursor, uint4* __restrict__ rec,
                                               float* __restrict__ partials){
    __shared__ float w1[64], w2[64];
    __shared__ float red[64];
    if (threadIdx.x < 64){ w1[threadIdx.x] = small[32+threadIdx.x]; w2[threadIdx.x] = small[96+threadIdx.x]; }
    __syncthreads();
    float cs[16];
#pragma unroll
    for (int k = 0; k < 16; ++k) cs[k] = 0.f;
    int stride = gridDim.x*blockDim.x;
    for (int e = blockIdx.x*blockDim.x + threadIdx.x; e < E_EDGES; e += stride){
        const float4* eap = (const float4*)(ea + (size_t)e*16);
        float ae1[4] = {0,0,0,0}, ae2[4] = {0,0,0,0};
#pragma unroll
        for (int q = 0; q < 4; ++q){
            float4 v4 = eap[q];
            float vv[4] = {v4.x, v4.y, v4.z, v4.w};
#pragma unroll
            for (int r = 0; r < 4; ++r){
                int k = q*4 + r;
                float xv = vv[r];
                cs[k] += xv;
#pragma unroll
                for (int hh = 0; hh < 4; ++hh){
                    ae1[hh] = fmaf(xv, w1[k*4+hh], ae1[hh]);
                    ae2[hh] = fmaf(xv, w2[k*4+hh], ae2[hh]);
                }
            }
        }
        int s = src[e], d = dst[e];
        const float4 as4 = *(const float4*)(a_s + (size_t)s*4);
        const float4 ad4 = *(const float4*)(a_d + (size_t)d*4);
        float wv0 = __expf(lrelu(as4.x + ad4.x + ae1[0]));
        float wv1 = __expf(lrelu(as4.y + ad4.y + ae1[1]));
        float wv2 = __expf(lrelu(as4.z + ad4.z + ae1[2]));
        float wv3 = __expf(lrelu(as4.w + ad4.w + ae1[3]));
        int p = atomicAdd(&cursor[d], 1);
        uint4 r0, r1;
        r0.x = (unsigned)s;
        r0.y = bf16rn(wv0) | (bf16rn(wv1) << 16);
        r0.z = bf16rn(wv2) | (bf16rn(wv3) << 16);
        r0.w = (unsigned)d;
        r1.x = bf16rn(ae2[0]) | (bf16rn(ae2[1]) << 16);
        r1.y = bf16rn(ae2[2]) | (bf16rn(ae2[3]) << 16);
        r1.z = 0u; r1.w = 0u;
        rec[(size_t)p*2]     = r0;
        rec[(size_t)p*2 + 1] = r1;
    }
#pragma unroll
    for (int k = 0; k < 16; ++k){
        float v = cs[k];
        v += __shfl_xor(v,1); v += __shfl_xor(v,2); v += __shfl_xor(v,4);
        v += __shfl_xor(v,8); v += __shfl_xor(v,16); v += __shfl_xor(v,32);
        if ((threadIdx.x & 63) == 0) red[k*4 + (threadIdx.x>>6)] = v;
    }
    __syncthreads();
    if (threadIdx.x < 16){
        float v = red[threadIdx.x*4] + red[threadIdx.x*4+1] + red[threadIdx.x*4+2] + red[threadIdx.x*4+3];
        partials[blockIdx.x*16 + threadIdx.x] = v;
    }
}

__global__ __launch_bounds__(256) void k_prep2(float* __restrict__ small, const float* __restrict__ partials){
    __shared__ float sm[256];
    __shared__ float mean_s[16];
    int t = threadIdx.x;
    float v = 0.f;
    for (int r = (t>>4); r < EDGE_BLOCKS; r += 16) v += partials[r*16 + (t&15)];
    sm[t] = v;
    __syncthreads();
    if (t < 16){
        float s = 0.f;
#pragma unroll
        for (int i = 0; i < 16; ++i) s += sm[t + 16*i];
        float m = s * (1.0f/(float)E_EDGES);
        mean_s[t] = m; small[16+t] = m;
    }
    __syncthreads();
    if (t < 4){
        float a1 = 0.f, a2 = 0.f;
#pragma unroll
        for (int k = 0; k < 16; ++k){
            a1 = fmaf(mean_s[k], small[32 + k*4 + t], a1);
            a2 = fmaf(mean_s[k], small[96 + k*4 + t], a2);
        }
        small[160+t] = a1; small[164+t] = a2;
    }
}

// Layer-2 weight pass: thread-per-CSR-slot, linear streams. Reads rec, gathers
// a_s2/a_d2 (L2-resident), writes compact c2 = {si, w2pk01, w2pk23, 0}.
__global__ __launch_bounds__(256) void k_w2(const uint4* __restrict__ rec,
                                            const float* __restrict__ a_s, const float* __restrict__ a_d,
                                            uint4* __restrict__ c2){
    int p = blockIdx.x*256 + threadIdx.x;
    if (p >= E_EDGES) return;
    uint4 r0 = rec[(size_t)p*2];
    uint2 r1 = *(const uint2*)&rec[(size_t)p*2 + 1];
    int si = (int)r0.x, d = (int)r0.w;
    const float4 as4 = *(const float4*)(a_s + (size_t)si*4);
    const float4 ad4 = *(const float4*)(a_d + (size_t)d*4);
    float w0 = __expf(lrelu(as4.x + ad4.x + bfsel(r1.x, 0)));
    float w1 = __expf(lrelu(as4.y + ad4.y + bfsel(r1.x, 1)));
    float w2 = __expf(lrelu(as4.z + ad4.z + bfsel(r1.y, 0)));
    float w3 = __expf(lrelu(as4.w + ad4.w + bfsel(r1.y, 1)));
    uint4 o;
    o.x = r0.x;
    o.y = bf16rn(w0) | (bf16rn(w1) << 16);
    o.z = bf16rn(w2) | (bf16rn(w3) << 16);
    o.w = 0u;
    c2[p] = o;
}

// One wave per node, lane = head*16+chan. Per edge: ONE uniform 16B record
// {si, wpk01, wpk23, _} (STRIDE uint4s apart) + one hb gather + 2 fma.
template<int STRIDE>
__global__ __launch_bounds__(256) void k_agg(const uint4* __restrict__ recs, const int* __restrict__ base,
                                             const unsigned short* __restrict__ hb,
                                             const float* __restrict__ a_s, const float* __restrict__ a_d,
                                             const float* __restrict__ aeloop, const float* __restrict__ bias,
                                             float* __restrict__ out){
    int lane = threadIdx.x & 63;
    int n = blockIdx.x*4 + (threadIdx.x >> 6);
    int hh = lane >> 4;
    int hi = hh & 1;
    float wL = __expf(lrelu(a_s[n*4+hh] + a_d[n*4+hh] + aeloop[hh]));
    float s0 = wL, s1 = 0.f;
    float acc0 = wL * bf2f(hb[(size_t)n*64 + lane]), acc1 = 0.f;
    int b0 = base[n], b1 = base[n+1];
    int p = b0;
    for (; p + 2 <= b1; p += 2){
        uint4 rA = recs[(size_t)p*STRIDE];
        uint4 rB = recs[(size_t)(p+1)*STRIDE];
        float hvA = bf2f(hb[(size_t)rA.x*64 + lane]);
        float hvB = bf2f(hb[(size_t)rB.x*64 + lane]);
        float wA = bfsel((hh < 2) ? rA.y : rA.z, hi);
        float wB = bfsel((hh < 2) ? rB.y : rB.z, hi);
        s0 += wA; acc0 = fmaf(wA, hvA, acc0);
        s1 += wB; acc1 = fmaf(wB, hvB, acc1);
    }
    if (p < b1){
        uint4 r = recs[(size_t)p*STRIDE];
        float hv = bf2f(hb[(size_t)r.x*64 + lane]);
        float w = bfsel((hh < 2) ? r.y : r.z, hi);
        s1 += w; acc1 = fmaf(w, hv, acc1);
    }
    float s = s0 + s1;
    float val = (acc0 + acc1) / (s + 1e-16f) + bias[lane];
    out[(size_t)n*64 + lane] = fmaxf(val, 0.f);
}

__global__ __launch_bounds__(256) void k_head(const float* __restrict__ h2,
                                              const float* __restrict__ lw1, const float* __restrict__ lb1,
                                              const float* __restrict__ lw2, const float* __restrict__ lb2,
                                              float* __restrict__ out){
    int n = blockIdx.x*256 + threadIdx.x;
    if (n >= N_NODES) return;
    float y16[16];
#pragma unroll
    for (int j = 0; j < 16; ++j) y16[j] = lb1[j];
    const float4* hp = (const float4*)(h2 + (size_t)n*64);
#pragma unroll
    for (int k4 = 0; k4 < 16; ++k4){
        float4 hv = hp[k4];
        float hvv[4] = {hv.x, hv.y, hv.z, hv.w};
#pragma unroll
        for (int r = 0; r < 4; ++r){
            float x = hvv[r];
            int k = k4*4 + r;
#pragma unroll
            for (int j = 0; j < 16; ++j) y16[j] = fmaf(x, lw1[k*16+j], y16[j]);
        }
    }
    float y[40];
#pragma unroll
    for (int o = 0; o < 40; ++o) y[o] = lb2[o];
#pragma unroll
    for (int j = 0; j < 16; ++j){
        float x = y16[j];
#pragma unroll
        for (int o = 0; o < 40; ++o) y[o] = fmaf(x, lw2[j*40+o], y[o]);
    }
    float mx = y[0];
#pragma unroll
    for (int o = 1; o < 40; ++o) mx = fmaxf(mx, y[o]);
    float sum = 0.f;
#pragma unroll
    for (int o = 0; o < 40; ++o) sum += __expf(y[o] - mx);
    float ls = __logf(sum) + mx;
    float* op = out + (size_t)n*40;
#pragma unroll
    for (int o = 0; o < 40; ++o) op[o] = y[o] - ls;
}

extern "C" void kernel_launch(void* const* d_in, const int* in_sizes, int n_in,
                              void* d_out, int out_size, void* d_ws, size_t ws_size,
                              hipStream_t stream){
    const float* x     = (const float*)d_in[0];
    const int*   ei    = (const int*)  d_in[1];
    const float* ea    = (const float*)d_in[2];
    const float* W1    = (const float*)d_in[3];
    const float* atts1 = (const float*)d_in[4];
    const float* attd1 = (const float*)d_in[5];
    const float* We1   = (const float*)d_in[6];
    const float* atte1 = (const float*)d_in[7];
    const float* b1    = (const float*)d_in[8];
    const float* W2    = (const float*)d_in[9];
    const float* atts2 = (const float*)d_in[10];
    const float* attd2 = (const float*)d_in[11];
    const float* We2   = (const float*)d_in[12];
    const float* atte2 = (const float*)d_in[13];
    const float* b2    = (const float*)d_in[14];
    const float* lw1   = (const float*)d_in[15];
    const float* lb1   = (const float*)d_in[16];
    const float* lw2   = (const float*)d_in[17];
    const float* lb2   = (const float*)d_in[18];
    float* outp = (float*)d_out;

    const int* srcp = ei;
    const int* dstp = ei + E_EDGES;

    char* ws = (char*)d_ws;
    size_t off = 0;
    auto alloc = [&](size_t bytes) -> void* {
        void* p = ws + off;
        off = (off + bytes + 255) & ~(size_t)255;
        return p;
    };
    float*  smallf   = (float*) alloc(256*sizeof(float));
    float*  partials = (float*) alloc((size_t)EDGE_BLOCKS*16*sizeof(float));
    int*    deg      = (int*)   alloc((size_t)N_NODES*sizeof(int));
    int*    base     = (int*)   alloc((size_t)(N_NODES+1)*sizeof(int));
    int*    cursor   = (int*)   alloc((size_t)N_NODES*sizeof(int));
    int*    bsum     = (int*)   alloc((size_t)(SCAN_BLOCKS+1)*sizeof(int));
    int*    boff     = (int*)   alloc((size_t)(SCAN_BLOCKS+1)*sizeof(int));
    uint4*  rec      = (uint4*) alloc((size_t)E_EDGES*32);
    uint4*  c2       = (uint4*) alloc((size_t)E_EDGES*16);
    unsigned short* hb = (unsigned short*)alloc((size_t)N_NODES*64*sizeof(unsigned short));
    float*  obuf     = (float*) alloc((size_t)N_NODES*64*sizeof(float));
    float*  asb      = (float*) alloc((size_t)N_NODES*4*sizeof(float));
    float*  adb      = (float*) alloc((size_t)N_NODES*4*sizeof(float));

    const int NB = N_NODES/4;             // 12500
    const int HB = (N_NODES + 255)/256;   // 196
    const int EB = (E_EDGES + 255)/256;   // 6250

    hipMemsetAsync(deg, 0, (size_t)N_NODES*sizeof(int), stream);
    k_prep1<<<1, 64, 0, stream>>>(We1, atte1, We2, atte2, smallf);
    k_hist<<<(E_EDGES/4 + 255)/256, 256, 0, stream>>>((const int4*)dstp, deg);
    k_scan_a<<<SCAN_BLOCKS, 256, 0, stream>>>(deg, bsum);
    k_scan_b<<<1, 256, 0, stream>>>(bsum, boff);
    k_scan_c<<<SCAN_BLOCKS, 256, 0, stream>>>(deg, boff, base, cursor);

    // ---- layer 1 ----
    k_node<128><<<NB, 256, 0, stream>>>(x, W1, atts1, attd1, hb, asb, adb);
    k_edges<<<EDGE_BLOCKS, 256, 0, stream>>>(srcp, dstp, ea, smallf, asb, adb,
                                             cursor, rec, partials);
    k_prep2<<<1, 256, 0, stream>>>(smallf, partials);
    k_agg<2><<<NB, 256, 0, stream>>>(rec, base, hb, asb, adb, smallf + 160, b1, obuf);

    // ---- layer 2 ----
    k_node<64><<<NB, 256, 0, stream>>>(obuf, W2, atts2, attd2, hb, asb, adb);
    k_w2<<<EB, 256, 0, stream>>>(rec, asb, adb, c2);
    k_agg<1><<<NB, 256, 0, stream>>>(c2, base, hb, asb, adb, smallf + 164, b2, obuf);

    // ---- head ----
    k_head<<<HB, 256, 0, stream>>>(obuf, lw1, lb1, lw2, lb2, outp);
}